// Round 8
// baseline (358.225 us; speedup 1.0000x reference)
//
#include <hip/hip_runtime.h>
#include <stdint.h>

#define B_ 2
#define S_ 2048
#define D_ 2048
#define H_ 16
#define KVH_ 4
#define HD_ 128
#define ROT_ 64
#define WINDOW_ 1024
#define EPS_ 1e-6f
#define M_ (B_ * S_)
#define NQKV_ 3072

#define KVBLK 64
#define LOG2E 1.44269504088896340736f
#define DEFER_THR 8.0f

typedef unsigned short ushort_t;
typedef _Float16 f16;
typedef float f32x4 __attribute__((ext_vector_type(4)));
typedef f16 f16x8 __attribute__((ext_vector_type(8)));

#define NINF (-__builtin_inff())
#define EXP2F(x) __builtin_exp2f(x)

// async global->LDS, 16B per lane. dst must be wave-uniform; HW adds lane*16.
__device__ __forceinline__ void gload16(const void* g, void* l) {
  __builtin_amdgcn_global_load_lds(
      (const __attribute__((address_space(1))) void*)g,
      (__attribute__((address_space(3))) void*)l, 16, 0, 0);
}

// ---------------- cast x (f32 -> f16), 8 elems/thread ----------------
__launch_bounds__(256, 4)
__global__ void cast_f32_f16(const float* __restrict__ src, f16* __restrict__ dst, int n8) {
  int i = blockIdx.x * 256 + threadIdx.x;
  if (i >= n8) return;
  float4 a = reinterpret_cast<const float4*>(src)[i * 2];
  float4 b = reinterpret_cast<const float4*>(src)[i * 2 + 1];
  f16x8 o = { (f16)a.x, (f16)a.y, (f16)a.z, (f16)a.w,
              (f16)b.x, (f16)b.y, (f16)b.z, (f16)b.w };
  reinterpret_cast<f16x8*>(dst)[i] = o;
}

// ---------------- transpose f32 [R][C] -> f16 [C][R] ----------------
__launch_bounds__(256, 4)
__global__ void transpose_f32_f16(const float* __restrict__ src, f16* __restrict__ dst,
                                  int R, int C) {
  __shared__ float tile[32][33];
  int c0 = blockIdx.x * 32, r0 = blockIdx.y * 32;
  int tx = threadIdx.x & 31, ty = threadIdx.x >> 5;
#pragma unroll
  for (int i = 0; i < 32; i += 8)
    tile[ty + i][tx] = src[(size_t)(r0 + ty + i) * C + c0 + tx];
  __syncthreads();
#pragma unroll
  for (int i = 0; i < 32; i += 8)
    dst[(size_t)(c0 + ty + i) * R + r0 + tx] = (f16)tile[tx][ty + i];
}

// ---------------- batched transpose 16-bit [R][C] -> [C][R] ----------------
__launch_bounds__(256, 4)
__global__ void transpose16(const ushort_t* __restrict__ src, ushort_t* __restrict__ dst,
                            int R, int C) {
  __shared__ ushort_t tile[32][33];
  size_t base = (size_t)blockIdx.z * R * C;
  src += base; dst += base;
  int c0 = blockIdx.x * 32, r0 = blockIdx.y * 32;
  int tx = threadIdx.x & 31, ty = threadIdx.x >> 5;
#pragma unroll
  for (int i = 0; i < 32; i += 8)
    tile[ty + i][tx] = src[(size_t)(r0 + ty + i) * C + c0 + tx];
  __syncthreads();
#pragma unroll
  for (int i = 0; i < 32; i += 8)
    dst[(size_t)(c0 + ty + i) * R + r0 + tx] = tile[tx][ty + i];
}

// ---------------- fp16 GEMM (round-5 proven): single-buffered, 2 barriers ------
__launch_bounds__(256, 2)
__global__ void gemm_f16(const f16* __restrict__ A, const f16* __restrict__ Bt,
                         float* __restrict__ C, int M, int N, int K) {
  __shared__ __attribute__((aligned(16))) f16 As[128][64];
  __shared__ __attribute__((aligned(16))) f16 Bs[128][64];
  const int gx = gridDim.x;
  const int nwg = gx * gridDim.y;
  const int flat = blockIdx.y * gx + blockIdx.x;
  const int q8 = nwg >> 3;
  const int id2 = (flat & 7) * q8 + (flat >> 3);
  const int bm = (id2 / gx) * 128, bn = (id2 % gx) * 128;
  const int tid = threadIdx.x;
  const int lane = tid & 63, wid = tid >> 6;
  const int wm = (wid >> 1) * 64, wn = (wid & 1) * 64;
  const int rr = lane & 15, rg = lane >> 4;
  const int sw = (((lane & 7) ^ (lane >> 3)) << 4);
  const int srw = lane >> 3;
  const char* Ab = (const char*)A + ((size_t)(bm + wid * 32 + srw) * K) * 2 + sw;
  const char* Bb = (const char*)Bt + ((size_t)(bn + wid * 32 + srw) * K) * 2 + sw;
  f32x4 acc[4][4] = {};
  for (int k0 = 0; k0 < K; k0 += 64) {
    __syncthreads();   // WAR: all waves done reading previous tile
#pragma unroll
    for (int g = 0; g < 4; ++g) {
      gload16(Ab + (size_t)(g * 8) * K * 2 + (size_t)k0 * 2,
              (char*)&As[0][0] + (wid * 32 + g * 8) * 128);
      gload16(Bb + (size_t)(g * 8) * K * 2 + (size_t)k0 * 2,
              (char*)&Bs[0][0] + (wid * 32 + g * 8) * 128);
    }
    __syncthreads();   // RAW: barrier drains vmcnt -> staged data visible
    f16x8 af[4][2], bf[4][2];
#pragma unroll
    for (int i = 0; i < 4; ++i)
#pragma unroll
      for (int kk = 0; kk < 2; ++kk) {
        af[i][kk] = *reinterpret_cast<const f16x8*>(
            (const char*)&As[0][0] + (wm + i * 16 + rr) * 128 +
            ((kk * 64 + rg * 16) ^ ((rr & 7) << 4)));
        bf[i][kk] = *reinterpret_cast<const f16x8*>(
            (const char*)&Bs[0][0] + (wn + i * 16 + rr) * 128 +
            ((kk * 64 + rg * 16) ^ ((rr & 7) << 4)));
      }
#pragma unroll
    for (int kk = 0; kk < 2; ++kk)
#pragma unroll
      for (int i = 0; i < 4; ++i)
#pragma unroll
        for (int j = 0; j < 4; ++j)
          acc[i][j] = __builtin_amdgcn_mfma_f32_16x16x32_f16(af[i][kk], bf[j][kk],
                                                             acc[i][j], 0, 0, 0);
  }
#pragma unroll
  for (int i = 0; i < 4; ++i)
#pragma unroll
    for (int j = 0; j < 4; ++j)
#pragma unroll
      for (int r = 0; r < 4; ++r)
        C[(size_t)(bm + wm + i * 16 + rg * 4 + r) * N + (bn + wn + j * 16 + rr)] = acc[i][j][r];
}

// ---------------- RMSNorm + RoPE for K and V, fp16 out ----------------
// K is pre-scaled by LOG2E so QK^T logits are in log2 units.
__launch_bounds__(256, 4)
__global__ void norm_rope_kv(const float* __restrict__ qkv, const float* __restrict__ cosb,
                             const float* __restrict__ sinb, const float* __restrict__ ksc,
                             f16* __restrict__ kf, f16* __restrict__ vb) {
  int gw = blockIdx.x * 4 + (threadIdx.x >> 6);
  int lane = threadIdx.x & 63;
  int row = gw >> 3, c = gw & 7;
  int b = row >> 11, s = row & (S_ - 1);
  int col = (c < 4) ? (2048 + c * 128) : (2560 + (c - 4) * 128);
  const float* src = qkv + (size_t)row * NQKV_ + col;
  float2 v = *reinterpret_cast<const float2*>(src + lane * 2);
  float ss = v.x * v.x + v.y * v.y;
#pragma unroll
  for (int off = 32; off; off >>= 1) ss += __shfl_xor(ss, off);
  float inv = rsqrtf(ss * (1.0f / HD_) + EPS_);
  float x0 = v.x * inv, x1 = v.y * inv;
  int d0 = lane * 2;
  f16* dst;
  size_t idx;
  if (c < 4) {  // k: (1+scale) then rope on dims [0,64), then *LOG2E
    x0 *= (1.0f + ksc[d0]);
    x1 *= (1.0f + ksc[d0 + 1]);
    float y0 = __shfl_xor(x0, 16);
    float y1 = __shfl_xor(x1, 16);
    if (d0 < ROT_) {
      int dm = d0 & 31;
      float cs0 = cosb[s * 32 + dm],     sn0 = sinb[s * 32 + dm];
      float cs1 = cosb[s * 32 + dm + 1], sn1 = sinb[s * 32 + dm + 1];
      if (d0 < 32) { x0 = x0 * cs0 - y0 * sn0; x1 = x1 * cs1 - y1 * sn1; }
      else         { x0 = x0 * cs0 + y0 * sn0; x1 = x1 * cs1 + y1 * sn1; }
    }
    x0 *= LOG2E; x1 *= LOG2E;
    dst = kf; idx = ((size_t)((b * KVH_ + c) * S_ + s)) * HD_ + d0;
  } else {      // v: plain rmsnorm
    dst = vb; idx = ((size_t)((b * KVH_ + (c - 4)) * S_ + s)) * HD_ + d0;
  }
  f16 o[2] = { (f16)x0, (f16)x1 };
  unsigned int pk; __builtin_memcpy(&pk, o, 4);
  *reinterpret_cast<unsigned int*>(dst + idx) = pk;
}

// ---------------- flash attention v6: de-staged, wave-independent ----------------
// 1024 blocks x 256 thr (4 waves). id&7 -> (b,kvh) pinned to one XCD (K/V = 1MB,
// L2-fits -> NO LDS staging, K/V MFMA fragments read DIRECTLY from global/L2).
// Each wave owns 16 q rows; waves of a block take q-groups j, j+32, j+64, j+96
// (uniform per-block cost). No __syncthreads anywhere. P bounced via per-wave LDS.
__launch_bounds__(256, 4)
__global__ void flash_attn(const float* __restrict__ qkv, const float* __restrict__ cosb,
                           const float* __restrict__ sinb, const float* __restrict__ qsc,
                           const f16* __restrict__ kfp, const f16* __restrict__ vt,
                           f16* __restrict__ ctxf) {
  __shared__ __attribute__((aligned(16))) f16 Pb[4][16][40];   // 5 KB
  const int id = blockIdx.x;
  const int g8 = id & 7, rest = id >> 3;          // rest in [0,128)
  const int b = g8 >> 2, kvh = g8 & 3;
  const int hh = rest >> 5, j = rest & 31;
  const int h = kvh * 4 + hh;
  const int lane = threadIdx.x & 63, w = threadIdx.x >> 6;
  const int rr = lane & 15, rg = lane >> 4;
  const int qw = (j + 32 * w) * 16;               // this wave's 16 q rows
  const char* Kh = (const char*)(kfp + (size_t)(b * KVH_ + kvh) * S_ * HD_);
  const char* Vh = (const char*)(vt  + (size_t)(b * KVH_ + kvh) * HD_ * S_);

  // ---- q: load f32, rmsnorm, scale, rope, *LOG2E, cvt fp16 ----
  f16x8 qf[4];
  {
    const int srow = qw + rr;
    const float* qrow = qkv + (size_t)(b * S_ + srow) * NQKV_ + h * HD_;
    float qv[4][8];
    float ssq = 0.f;
#pragma unroll
    for (int kk = 0; kk < 4; ++kk) {
      float4 u0 = *reinterpret_cast<const float4*>(qrow + kk * 32 + rg * 8);
      float4 u1 = *reinterpret_cast<const float4*>(qrow + kk * 32 + rg * 8 + 4);
      qv[kk][0] = u0.x; qv[kk][1] = u0.y; qv[kk][2] = u0.z; qv[kk][3] = u0.w;
      qv[kk][4] = u1.x; qv[kk][5] = u1.y; qv[kk][6] = u1.z; qv[kk][7] = u1.w;
#pragma unroll
      for (int j2 = 0; j2 < 8; ++j2) ssq += qv[kk][j2] * qv[kk][j2];
    }
    ssq += __shfl_xor(ssq, 16);
    ssq += __shfl_xor(ssq, 32);
    float inv = rsqrtf(ssq * (1.0f / HD_) + EPS_);
#pragma unroll
    for (int kk = 0; kk < 4; ++kk)
#pragma unroll
      for (int j2 = 0; j2 < 8; ++j2)
        qv[kk][j2] *= inv * (1.0f + qsc[kk * 32 + rg * 8 + j2]);
    const float* cs = cosb + (size_t)srow * 32;
    const float* sn = sinb + (size_t)srow * 32;
#pragma unroll
    for (int j2 = 0; j2 < 8; ++j2) {
      int d = rg * 8 + j2;
      float c = cs[d], s = sn[d];
      float x0 = qv[0][j2], x1 = qv[1][j2];
      qv[0][j2] = x0 * c - x1 * s;
      qv[1][j2] = x1 * c + x0 * s;
    }
#pragma unroll
    for (int kk = 0; kk < 4; ++kk)
#pragma unroll
      for (int j2 = 0; j2 < 8; ++j2)
        qf[kk][j2] = (f16)qv[kk][j2];
  }

  f32x4 acc[8] = {};
  f32x4 accl = {};
  float m_run[4], msafe[4];
#pragma unroll
  for (int r = 0; r < 4; ++r) { m_run[r] = NINF; msafe[r] = 0.f; }
  const f16x8 ones = { (f16)1, (f16)1, (f16)1, (f16)1, (f16)1, (f16)1, (f16)1, (f16)1 };

  int kvStart = qw - (WINDOW_ - 1);
  if (kvStart < 0) kvStart = 0;
  kvStart &= ~(KVBLK - 1);
  const int ntile = ((qw + 16 - kvStart) + KVBLK - 1) >> 6;

  // per-lane fragment base addresses (bytes)
  const char* kl = Kh + (size_t)rr * 256 + rg * 16;       // + row*256 + kk*64
  const char* vl = Vh + (size_t)rr * (S_ * 2) + rg * 16;  // + n*16*S*2 + key0*2 (+64)

  for (int t = 0; t < ntile; ++t) {
    const int key0 = kvStart + t * KVBLK;

    // ---- QK^T: fragments straight from global (L2) ----
    f32x4 sc[4];
#pragma unroll
    for (int nt = 0; nt < 4; ++nt) {
      const char* kb = kl + (size_t)(key0 + nt * 16) * 256;
      f32x4 s = {};
#pragma unroll
      for (int kk = 0; kk < 4; ++kk) {
        f16x8 kfr = *reinterpret_cast<const f16x8*>(kb + kk * 64);
        s = __builtin_amdgcn_mfma_f32_16x16x32_f16(qf[kk], kfr, s, 0, 0, 0);
      }
      sc[nt] = s;
    }

    // ---- mask (skipped for interior tiles) ----
    const bool interior = (key0 + 63 <= qw) && (key0 >= qw - 1008);
    if (!interior) {
#pragma unroll
      for (int nt = 0; nt < 4; ++nt)
#pragma unroll
        for (int r = 0; r < 4; ++r) {
          int qi = qw + rg * 4 + r;
          int kj = key0 + nt * 16 + rr;
          bool valid = (kj <= qi) && (qi - kj < WINDOW_);
          if (!valid) sc[nt][r] = NINF;
        }
    }

    // ---- row max ----
    float tmax[4];
#pragma unroll
    for (int r = 0; r < 4; ++r)
      tmax[r] = fmaxf(fmaxf(sc[0][r], sc[1][r]), fmaxf(sc[2][r], sc[3][r]));
#pragma unroll
    for (int off = 1; off < 16; off <<= 1)
#pragma unroll
      for (int r = 0; r < 4; ++r)
        tmax[r] = fmaxf(tmax[r], __shfl_xor(tmax[r], off));

    // ---- defer-max: skip rescale when max growth <= THR ----
    bool defer = true;
#pragma unroll
    for (int r = 0; r < 4; ++r)
      defer = defer && (tmax[r] - m_run[r] <= DEFER_THR);
    if (!__all(defer)) {
      float alpha[4];
#pragma unroll
      for (int r = 0; r < 4; ++r) {
        float mn = fmaxf(m_run[r], tmax[r]);
        alpha[r] = (m_run[r] == NINF) ? 0.f : EXP2F(m_run[r] - mn);
        m_run[r] = mn;
        msafe[r] = (mn == NINF) ? 0.f : mn;
      }
#pragma unroll
      for (int n = 0; n < 8; ++n)
#pragma unroll
        for (int r = 0; r < 4; ++r) acc[n][r] *= alpha[r];
#pragma unroll
      for (int r = 0; r < 4; ++r) accl[r] *= alpha[r];
    }
    // P = 2^(s - msafe); bounded by 2^THR on deferred tiles
#pragma unroll
    for (int nt = 0; nt < 4; ++nt)
#pragma unroll
      for (int r = 0; r < 4; ++r)
        sc[nt][r] = EXP2F(sc[nt][r] - msafe[r]);

    // ---- P -> per-wave LDS (two passes), PV MFMA from global V^T ----
#pragma unroll
    for (int nt = 0; nt < 2; ++nt)
#pragma unroll
      for (int r = 0; r < 4; ++r)
        Pb[w][rg * 4 + r][nt * 16 + rr] = (f16)sc[nt][r];
    f16x8 pf0 = *reinterpret_cast<const f16x8*>(&Pb[w][rr][rg * 8]);
#pragma unroll
    for (int nt = 0; nt < 2; ++nt)
#pragma unroll
      for (int r = 0; r < 4; ++r)
        Pb[w][rg * 4 + r][nt * 16 + rr] = (f16)sc[2 + nt][r];
    f16x8 pf1 = *reinterpret_cast<const f16x8*>(&Pb[w][rr][rg * 8]);

    __builtin_amdgcn_s_setprio(1);
#pragma unroll
    for (int n = 0; n < 8; ++n) {
      const char* vb2 = vl + (size_t)n * 16 * (S_ * 2) + (size_t)key0 * 2;
      f16x8 vf0 = *reinterpret_cast<const f16x8*>(vb2);
      f16x8 vf1 = *reinterpret_cast<const f16x8*>(vb2 + 64);
      acc[n] = __builtin_amdgcn_mfma_f32_16x16x32_f16(pf0, vf0, acc[n], 0, 0, 0);
      acc[n] = __builtin_amdgcn_mfma_f32_16x16x32_f16(pf1, vf1, acc[n], 0, 0, 0);
    }
    accl = __builtin_amdgcn_mfma_f32_16x16x32_f16(pf0, ones, accl, 0, 0, 0);
    accl = __builtin_amdgcn_mfma_f32_16x16x32_f16(pf1, ones, accl, 0, 0, 0);
    __builtin_amdgcn_s_setprio(0);
  }

  // epilogue: normalize, write ctx fp16 contiguous [M][2048]
#pragma unroll
  for (int n = 0; n < 8; ++n)
#pragma unroll
    for (int r = 0; r < 4; ++r) {
      float o = acc[n][r] / accl[r];
      int qi = qw + rg * 4 + r;
      ctxf[(size_t)(b * S_ + qi) * D_ + h * HD_ + n * 16 + rr] = (f16)o;
    }
}

extern "C" void kernel_launch(void* const* d_in, const int* in_sizes, int n_in,
                              void* d_out, int out_size, void* d_ws, size_t ws_size,
                              hipStream_t stream) {
  const float* x    = (const float*)d_in[0];
  // d_in[1] = mask (recomputed analytically)
  const float* cosb = (const float*)d_in[2];
  const float* sinb = (const float*)d_in[3];
  const float* Wq   = (const float*)d_in[4];
  const float* Wk   = (const float*)d_in[5];
  const float* Wv   = (const float*)d_in[6];
  const float* Wo   = (const float*)d_in[7];
  const float* qsc  = (const float*)d_in[8];
  const float* ksc  = (const float*)d_in[9];
  float* out = (float*)d_out;

  char* ws = (char*)d_ws;
  const size_t MB = 1ull << 20;
  // [0,16)  xh fp16         -> after gemm0 reused: ctxf fp16
  // [16,28) wqkvT fp16      -> after gemm0 reused: kf[16,20) vb[20,24) vtb[24,28)
  // [28,36) woT fp16
  // [36,84) qkv f32
  f16* xh    = (f16*)(ws + 0 * MB);
  f16* ctxf  = (f16*)(ws + 0 * MB);
  f16* wqkvT = (f16*)(ws + 16 * MB);
  f16* kf    = (f16*)(ws + 16 * MB);
  f16* vb    = (f16*)(ws + 20 * MB);
  f16* vtb   = (f16*)(ws + 24 * MB);
  f16* woT   = (f16*)(ws + 28 * MB);
  float* qkv = (float*)(ws + 36 * MB);

  cast_f32_f16<<<dim3(M_ * D_ / 8 / 256), 256, 0, stream>>>(x, xh, M_ * D_ / 8);
  transpose_f32_f16<<<dim3(64, 64), 256, 0, stream>>>(Wq, wqkvT, D_, 2048);
  transpose_f32_f16<<<dim3(16, 64), 256, 0, stream>>>(Wk, wqkvT + (size_t)2048 * D_, D_, 512);
  transpose_f32_f16<<<dim3(16, 64), 256, 0, stream>>>(Wv, wqkvT + (size_t)2560 * D_, D_, 512);
  transpose_f32_f16<<<dim3(64, 64), 256, 0, stream>>>(Wo, woT, D_, D_);
  gemm_f16<<<dim3(NQKV_ / 128, M_ / 128), 256, 0, stream>>>(xh, wqkvT, qkv, M_, NQKV_, D_);
  norm_rope_kv<<<dim3(M_ * 8 / 4), 256, 0, stream>>>(qkv, cosb, sinb, ksc, kf, vb);
  transpose16<<<dim3(HD_ / 32, S_ / 32, B_ * KVH_), 256, 0, stream>>>(
      (const ushort_t*)vb, (ushort_t*)vtb, S_, HD_);
  flash_attn<<<dim3((S_ / 64) * H_ * B_), 256, 0, stream>>>(
      qkv, cosb, sinb, qsc, kf, vtb, ctxf);
  gemm_f16<<<dim3(D_ / 128, M_ / 128), 256, 0, stream>>>(ctxf, woT, out, M_, D_, D_);
}

// Round 10
// 222.673 us; speedup vs baseline: 1.6088x; 1.6088x over previous
//
#include <hip/hip_runtime.h>
#include <stdint.h>

#define B_ 2
#define S_ 2048
#define D_ 2048
#define H_ 16
#define KVH_ 4
#define HD_ 128
#define ROT_ 64
#define WINDOW_ 1024
#define EPS_ 1e-6f
#define M_ (B_ * S_)
#define NQKV_ 3072

#define QBLK 128
#define KVBLK 64
#define LOG2E 1.44269504088896340736f
#define DEFER_THR 8.0f

typedef unsigned short ushort_t;
typedef _Float16 f16;
typedef float f32x4 __attribute__((ext_vector_type(4)));
typedef f16 f16x8 __attribute__((ext_vector_type(8)));

#define NINF (-__builtin_inff())
#define EXP2F(x) __builtin_exp2f(x)

// async global->LDS, 16B per lane. dst must be wave-uniform; HW adds lane*16.
__device__ __forceinline__ void gload16(const void* g, void* l) {
  __builtin_amdgcn_global_load_lds(
      (const __attribute__((address_space(1))) void*)g,
      (__attribute__((address_space(3))) void*)l, 16, 0, 0);
}

// ---------------- cast x (f32 -> f16), 8 elems/thread ----------------
__launch_bounds__(256, 4)
__global__ void cast_f32_f16(const float* __restrict__ src, f16* __restrict__ dst, int n8) {
  int i = blockIdx.x * 256 + threadIdx.x;
  if (i >= n8) return;
  float4 a = reinterpret_cast<const float4*>(src)[i * 2];
  float4 b = reinterpret_cast<const float4*>(src)[i * 2 + 1];
  f16x8 o = { (f16)a.x, (f16)a.y, (f16)a.z, (f16)a.w,
              (f16)b.x, (f16)b.y, (f16)b.z, (f16)b.w };
  reinterpret_cast<f16x8*>(dst)[i] = o;
}

// ---------------- transpose f32 [R][C] -> f16 [C][R] ----------------
__launch_bounds__(256, 4)
__global__ void transpose_f32_f16(const float* __restrict__ src, f16* __restrict__ dst,
                                  int R, int C) {
  __shared__ float tile[32][33];
  int c0 = blockIdx.x * 32, r0 = blockIdx.y * 32;
  int tx = threadIdx.x & 31, ty = threadIdx.x >> 5;
#pragma unroll
  for (int i = 0; i < 32; i += 8)
    tile[ty + i][tx] = src[(size_t)(r0 + ty + i) * C + c0 + tx];
  __syncthreads();
#pragma unroll
  for (int i = 0; i < 32; i += 8)
    dst[(size_t)(c0 + ty + i) * R + r0 + tx] = (f16)tile[tx][ty + i];
}

// ---------------- batched transpose 16-bit [R][C] -> [C][R] ----------------
__launch_bounds__(256, 4)
__global__ void transpose16(const ushort_t* __restrict__ src, ushort_t* __restrict__ dst,
                            int R, int C) {
  __shared__ ushort_t tile[32][33];
  size_t base = (size_t)blockIdx.z * R * C;
  src += base; dst += base;
  int c0 = blockIdx.x * 32, r0 = blockIdx.y * 32;
  int tx = threadIdx.x & 31, ty = threadIdx.x >> 5;
#pragma unroll
  for (int i = 0; i < 32; i += 8)
    tile[ty + i][tx] = src[(size_t)(r0 + ty + i) * C + c0 + tx];
  __syncthreads();
#pragma unroll
  for (int i = 0; i < 32; i += 8)
    dst[(size_t)(c0 + ty + i) * R + r0 + tx] = tile[tx][ty + i];
}

// ---------------- fp16 GEMM (round-5 proven): single-buffered, 2 barriers ------
__launch_bounds__(256, 2)
__global__ void gemm_f16(const f16* __restrict__ A, const f16* __restrict__ Bt,
                         float* __restrict__ C, int M, int N, int K) {
  __shared__ __attribute__((aligned(16))) f16 As[128][64];
  __shared__ __attribute__((aligned(16))) f16 Bs[128][64];
  const int gx = gridDim.x;
  const int nwg = gx * gridDim.y;
  const int flat = blockIdx.y * gx + blockIdx.x;
  const int q8 = nwg >> 3;
  const int id2 = (flat & 7) * q8 + (flat >> 3);
  const int bm = (id2 / gx) * 128, bn = (id2 % gx) * 128;
  const int tid = threadIdx.x;
  const int lane = tid & 63, wid = tid >> 6;
  const int wm = (wid >> 1) * 64, wn = (wid & 1) * 64;
  const int rr = lane & 15, rg = lane >> 4;
  const int sw = (((lane & 7) ^ (lane >> 3)) << 4);
  const int srw = lane >> 3;
  const char* Ab = (const char*)A + ((size_t)(bm + wid * 32 + srw) * K) * 2 + sw;
  const char* Bb = (const char*)Bt + ((size_t)(bn + wid * 32 + srw) * K) * 2 + sw;
  f32x4 acc[4][4] = {};
  for (int k0 = 0; k0 < K; k0 += 64) {
    __syncthreads();   // WAR: all waves done reading previous tile
#pragma unroll
    for (int g = 0; g < 4; ++g) {
      gload16(Ab + (size_t)(g * 8) * K * 2 + (size_t)k0 * 2,
              (char*)&As[0][0] + (wid * 32 + g * 8) * 128);
      gload16(Bb + (size_t)(g * 8) * K * 2 + (size_t)k0 * 2,
              (char*)&Bs[0][0] + (wid * 32 + g * 8) * 128);
    }
    __syncthreads();   // RAW: barrier drains vmcnt -> staged data visible
    f16x8 af[4][2], bf[4][2];
#pragma unroll
    for (int i = 0; i < 4; ++i)
#pragma unroll
      for (int kk = 0; kk < 2; ++kk) {
        af[i][kk] = *reinterpret_cast<const f16x8*>(
            (const char*)&As[0][0] + (wm + i * 16 + rr) * 128 +
            ((kk * 64 + rg * 16) ^ ((rr & 7) << 4)));
        bf[i][kk] = *reinterpret_cast<const f16x8*>(
            (const char*)&Bs[0][0] + (wn + i * 16 + rr) * 128 +
            ((kk * 64 + rg * 16) ^ ((rr & 7) << 4)));
      }
#pragma unroll
    for (int kk = 0; kk < 2; ++kk)
#pragma unroll
      for (int i = 0; i < 4; ++i)
#pragma unroll
        for (int j = 0; j < 4; ++j)
          acc[i][j] = __builtin_amdgcn_mfma_f32_16x16x32_f16(af[i][kk], bf[j][kk],
                                                             acc[i][j], 0, 0, 0);
  }
#pragma unroll
  for (int i = 0; i < 4; ++i)
#pragma unroll
    for (int j = 0; j < 4; ++j)
#pragma unroll
      for (int r = 0; r < 4; ++r)
        C[(size_t)(bm + wm + i * 16 + rg * 4 + r) * N + (bn + wn + j * 16 + rr)] = acc[i][j][r];
}

// ---------------- RMSNorm + RoPE for K and V, fp16 out ----------------
// K is pre-scaled by LOG2E so QK^T logits are in log2 units.
__launch_bounds__(256, 4)
__global__ void norm_rope_kv(const float* __restrict__ qkv, const float* __restrict__ cosb,
                             const float* __restrict__ sinb, const float* __restrict__ ksc,
                             f16* __restrict__ kf, f16* __restrict__ vb) {
  int gw = blockIdx.x * 4 + (threadIdx.x >> 6);
  int lane = threadIdx.x & 63;
  int row = gw >> 3, c = gw & 7;
  int b = row >> 11, s = row & (S_ - 1);
  int col = (c < 4) ? (2048 + c * 128) : (2560 + (c - 4) * 128);
  const float* src = qkv + (size_t)row * NQKV_ + col;
  float2 v = *reinterpret_cast<const float2*>(src + lane * 2);
  float ss = v.x * v.x + v.y * v.y;
#pragma unroll
  for (int off = 32; off; off >>= 1) ss += __shfl_xor(ss, off);
  float inv = rsqrtf(ss * (1.0f / HD_) + EPS_);
  float x0 = v.x * inv, x1 = v.y * inv;
  int d0 = lane * 2;
  f16* dst;
  size_t idx;
  if (c < 4) {  // k: (1+scale) then rope on dims [0,64), then *LOG2E
    x0 *= (1.0f + ksc[d0]);
    x1 *= (1.0f + ksc[d0 + 1]);
    float y0 = __shfl_xor(x0, 16);
    float y1 = __shfl_xor(x1, 16);
    if (d0 < ROT_) {
      int dm = d0 & 31;
      float cs0 = cosb[s * 32 + dm],     sn0 = sinb[s * 32 + dm];
      float cs1 = cosb[s * 32 + dm + 1], sn1 = sinb[s * 32 + dm + 1];
      if (d0 < 32) { x0 = x0 * cs0 - y0 * sn0; x1 = x1 * cs1 - y1 * sn1; }
      else         { x0 = x0 * cs0 + y0 * sn0; x1 = x1 * cs1 + y1 * sn1; }
    }
    x0 *= LOG2E; x1 *= LOG2E;
    dst = kf; idx = ((size_t)((b * KVH_ + c) * S_ + s)) * HD_ + d0;
  } else {      // v: plain rmsnorm
    dst = vb; idx = ((size_t)((b * KVH_ + (c - 4)) * S_ + s)) * HD_ + d0;
  }
  f16 o[2] = { (f16)x0, (f16)x1 };
  unsigned int pk; __builtin_memcpy(&pk, o, 4);
  *reinterpret_cast<unsigned int*>(dst + idx) = pk;
}

// ---------------- flash attention v7b: staged, 4 waves x 32 q-rows ----------------
// 512 blocks x 256 thr (fix: was erroneously 256 blocks -> half the q-tiles dropped).
// id&7 -> (b,kvh) pinned to one XCD; heavy q-tiles (rest<32 -> qtile 8..15) first.
// Wave owns 32 q rows (2 row-blocks of 16) -> K/V LDS fragment reads amortized 2x.
// K [64][128] and V^T [128][64] double-buffered, global_load_lds w16, XOR swizzle
// ^((row&7)<<4). One barrier per tile. Fully-masked wave-tiles skip compute.
__launch_bounds__(256, 2)
__global__ void flash_attn(const float* __restrict__ qkv, const float* __restrict__ cosb,
                           const float* __restrict__ sinb, const float* __restrict__ qsc,
                           const f16* __restrict__ kfp, const f16* __restrict__ vt,
                           f16* __restrict__ ctxf) {
  __shared__ __attribute__((aligned(16))) f16 Ks[2][KVBLK][128];   // 32 KB
  __shared__ __attribute__((aligned(16))) f16 Vs[2][128][KVBLK];   // 32 KB
  __shared__ __attribute__((aligned(16))) f16 Pb[4][32][40];       // 10.2 KB
  const int id = blockIdx.x;
  const int g8 = id & 7, rest = id >> 3;          // rest in [0,64)
  const int b = g8 >> 2, kvh = g8 & 3;
  int hh, qtile;
  if (rest < 32) { hh = rest >> 3; qtile = 8 + (rest & 7); }     // heavy: 10..18 tiles
  else { int lv = rest - 32; hh = lv >> 3; qtile = lv & 7; }     // light: 2..16
  const int h = kvh * 4 + hh;
  const int lane = threadIdx.x & 63, w = threadIdx.x >> 6;
  const int rr = lane & 15, rg = lane >> 4;
  const int qBase = qtile * QBLK;
  const int qw = qBase + w * 32;                  // this wave's 32 q rows
  const f16* Kh = kfp + (size_t)(b * KVH_ + kvh) * S_ * HD_;
  const f16* Vh = vt  + (size_t)(b * KVH_ + kvh) * HD_ * S_;

  // ---- q: load f32, rmsnorm, scale, rope, *LOG2E, cvt fp16 (2 row-blocks) ----
  f16x8 qf[2][4];
#pragma unroll
  for (int rb = 0; rb < 2; ++rb) {
    const int srow = qw + rb * 16 + rr;
    const float* qrow = qkv + (size_t)(b * S_ + srow) * NQKV_ + h * HD_;
    float qv[4][8];
    float ssq = 0.f;
#pragma unroll
    for (int kk = 0; kk < 4; ++kk) {
      float4 u0 = *reinterpret_cast<const float4*>(qrow + kk * 32 + rg * 8);
      float4 u1 = *reinterpret_cast<const float4*>(qrow + kk * 32 + rg * 8 + 4);
      qv[kk][0] = u0.x; qv[kk][1] = u0.y; qv[kk][2] = u0.z; qv[kk][3] = u0.w;
      qv[kk][4] = u1.x; qv[kk][5] = u1.y; qv[kk][6] = u1.z; qv[kk][7] = u1.w;
#pragma unroll
      for (int j = 0; j < 8; ++j) ssq += qv[kk][j] * qv[kk][j];
    }
    ssq += __shfl_xor(ssq, 16);
    ssq += __shfl_xor(ssq, 32);
    float inv = rsqrtf(ssq * (1.0f / HD_) + EPS_);
#pragma unroll
    for (int kk = 0; kk < 4; ++kk)
#pragma unroll
      for (int j = 0; j < 8; ++j)
        qv[kk][j] *= inv * (1.0f + qsc[kk * 32 + rg * 8 + j]);
    const float* cs = cosb + (size_t)srow * 32;
    const float* sn = sinb + (size_t)srow * 32;
#pragma unroll
    for (int j = 0; j < 8; ++j) {
      int d = rg * 8 + j;
      float c = cs[d], s = sn[d];
      float x0 = qv[0][j], x1 = qv[1][j];
      qv[0][j] = x0 * c - x1 * s;
      qv[1][j] = x1 * c + x0 * s;
    }
#pragma unroll
    for (int kk = 0; kk < 4; ++kk)
#pragma unroll
      for (int j = 0; j < 8; ++j)
        qf[rb][kk][j] = (f16)qv[kk][j];
  }

  f32x4 acc[2][8] = {};
  f32x4 accl[2] = {};
  float m_run[2][4], msafe[2][4];
#pragma unroll
  for (int rb = 0; rb < 2; ++rb)
#pragma unroll
    for (int r = 0; r < 4; ++r) { m_run[rb][r] = NINF; msafe[rb][r] = 0.f; }
  const f16x8 ones = { (f16)1, (f16)1, (f16)1, (f16)1, (f16)1, (f16)1, (f16)1, (f16)1 };

  int kvStart = qBase - (WINDOW_ - 1);
  if (kvStart < 0) kvStart = 0;
  kvStart &= ~(KVBLK - 1);
  const int ntile = (qBase + QBLK - kvStart) >> 6;

  // staging lane mapping: K rows 16/wave (4 per issue), V d-rows 32/wave (8 per issue)
  const int k_r0 = lane >> 4;          // 0..3
  const int k_cb = (lane & 15) * 16;
  const int v_r0 = lane >> 3;          // 0..7
  const int v_cb = (lane & 7) * 16;

#define STAGE(bufs, key0_)                                                           \
  do {                                                                               \
    _Pragma("unroll")                                                                \
    for (int gg = 0; gg < 4; ++gg) {                                                 \
      int krow = gg * 4 + k_r0;                                                      \
      gload16((const char*)Kh + (size_t)((key0_) + w * 16 + krow) * 256 +            \
                  (k_cb ^ ((krow & 7) << 4)),                                        \
              (char*)&Ks[bufs][0][0] + (w * 16 + gg * 4) * 256);                     \
      int vrow = gg * 8 + v_r0;                                                      \
      gload16((const char*)Vh + (size_t)(w * 32 + vrow) * (S_ * 2) +                 \
                  (size_t)(key0_) * 2 + (v_cb ^ ((vrow & 7) << 4)),                  \
              (char*)&Vs[bufs][0][0] + (w * 32 + gg * 8) * 128);                     \
    }                                                                                \
  } while (0)

  STAGE(0, kvStart);
  __syncthreads();

  for (int t = 0; t < ntile; ++t) {
    const int key0 = kvStart + t * KVBLK;
    const int buf = t & 1;
    if (t + 1 < ntile) STAGE(buf ^ 1, key0 + KVBLK);

    // wave-level skip: tile fully masked for this wave's 32 rows
    const bool live = (key0 <= qw + 31) && (key0 + 63 >= qw - (WINDOW_ - 1));
    if (live) {
      // ---- QK^T: K frags shared across both row-blocks ----
      f32x4 sc[2][4];
#pragma unroll
      for (int nt = 0; nt < 4; ++nt) {
        const int rt = nt * 16 + rr;
        const char* kbase = (const char*)&Ks[buf][0][0] + rt * 256;
        const int swz = (rt & 7) << 4;
        f16x8 kfr[4];
#pragma unroll
        for (int kk = 0; kk < 4; ++kk)
          kfr[kk] = *reinterpret_cast<const f16x8*>(kbase + ((kk * 64 + rg * 16) ^ swz));
        f32x4 s0 = {}, s1 = {};
#pragma unroll
        for (int kk = 0; kk < 4; ++kk) {
          s0 = __builtin_amdgcn_mfma_f32_16x16x32_f16(qf[0][kk], kfr[kk], s0, 0, 0, 0);
          s1 = __builtin_amdgcn_mfma_f32_16x16x32_f16(qf[1][kk], kfr[kk], s1, 0, 0, 0);
        }
        sc[0][nt] = s0; sc[1][nt] = s1;
      }

      // ---- mask (skipped for interior tiles) ----
      const bool interior = (key0 + 63 <= qw) && (key0 >= qw - 992);
      if (!interior) {
#pragma unroll
        for (int rb = 0; rb < 2; ++rb)
#pragma unroll
          for (int nt = 0; nt < 4; ++nt)
#pragma unroll
            for (int r = 0; r < 4; ++r) {
              int qi = qw + rb * 16 + rg * 4 + r;
              int kj = key0 + nt * 16 + rr;
              bool valid = (kj <= qi) && (qi - kj < WINDOW_);
              if (!valid) sc[rb][nt][r] = NINF;
            }
      }

      // ---- row max + defer-max ----
      float tmax[2][4];
#pragma unroll
      for (int rb = 0; rb < 2; ++rb)
#pragma unroll
        for (int r = 0; r < 4; ++r)
          tmax[rb][r] = fmaxf(fmaxf(sc[rb][0][r], sc[rb][1][r]),
                              fmaxf(sc[rb][2][r], sc[rb][3][r]));
#pragma unroll
      for (int off = 1; off < 16; off <<= 1)
#pragma unroll
        for (int rb = 0; rb < 2; ++rb)
#pragma unroll
          for (int r = 0; r < 4; ++r)
            tmax[rb][r] = fmaxf(tmax[rb][r], __shfl_xor(tmax[rb][r], off));

      bool defer = true;
#pragma unroll
      for (int rb = 0; rb < 2; ++rb)
#pragma unroll
        for (int r = 0; r < 4; ++r)
          defer = defer && (tmax[rb][r] - m_run[rb][r] <= DEFER_THR);
      if (!__all(defer)) {
#pragma unroll
        for (int rb = 0; rb < 2; ++rb) {
          float alpha[4];
#pragma unroll
          for (int r = 0; r < 4; ++r) {
            float mn = fmaxf(m_run[rb][r], tmax[rb][r]);
            alpha[r] = (m_run[rb][r] == NINF) ? 0.f : EXP2F(m_run[rb][r] - mn);
            m_run[rb][r] = mn;
            msafe[rb][r] = (mn == NINF) ? 0.f : mn;
          }
#pragma unroll
          for (int n = 0; n < 8; ++n)
#pragma unroll
            for (int r = 0; r < 4; ++r) acc[rb][n][r] *= alpha[r];
#pragma unroll
          for (int r = 0; r < 4; ++r) accl[rb][r] *= alpha[r];
        }
      }
#pragma unroll
      for (int rb = 0; rb < 2; ++rb)
#pragma unroll
        for (int nt = 0; nt < 4; ++nt)
#pragma unroll
          for (int r = 0; r < 4; ++r)
            sc[rb][nt][r] = EXP2F(sc[rb][nt][r] - msafe[rb][r]);

      // ---- P -> LDS (two passes over 32-key halves), PV MFMA ----
      f16x8 pf[2][2];
#pragma unroll
      for (int p = 0; p < 2; ++p) {
#pragma unroll
        for (int rb = 0; rb < 2; ++rb)
#pragma unroll
          for (int nt2 = 0; nt2 < 2; ++nt2)
#pragma unroll
            for (int r = 0; r < 4; ++r)
              Pb[w][rb * 16 + rg * 4 + r][nt2 * 16 + rr] = (f16)sc[rb][p * 2 + nt2][r];
        pf[0][p] = *reinterpret_cast<const f16x8*>(&Pb[w][rr][rg * 8]);
        pf[1][p] = *reinterpret_cast<const f16x8*>(&Pb[w][16 + rr][rg * 8]);
      }

      __builtin_amdgcn_s_setprio(1);
#pragma unroll
      for (int n = 0; n < 8; ++n) {
        const int d = n * 16 + rr;
        const char* vbase = (const char*)&Vs[buf][0][0] + d * 128;
        const int swz = (d & 7) << 4;
        f16x8 vf0 = *reinterpret_cast<const f16x8*>(vbase + ((rg * 16) ^ swz));
        f16x8 vf1 = *reinterpret_cast<const f16x8*>(vbase + ((64 + rg * 16) ^ swz));
        acc[0][n] = __builtin_amdgcn_mfma_f32_16x16x32_f16(pf[0][0], vf0, acc[0][n], 0, 0, 0);
        acc[0][n] = __builtin_amdgcn_mfma_f32_16x16x32_f16(pf[0][1], vf1, acc[0][n], 0, 0, 0);
        acc[1][n] = __builtin_amdgcn_mfma_f32_16x16x32_f16(pf[1][0], vf0, acc[1][n], 0, 0, 0);
        acc[1][n] = __builtin_amdgcn_mfma_f32_16x16x32_f16(pf[1][1], vf1, acc[1][n], 0, 0, 0);
      }
#pragma unroll
      for (int rb = 0; rb < 2; ++rb) {
        accl[rb] = __builtin_amdgcn_mfma_f32_16x16x32_f16(pf[rb][0], ones, accl[rb], 0, 0, 0);
        accl[rb] = __builtin_amdgcn_mfma_f32_16x16x32_f16(pf[rb][1], ones, accl[rb], 0, 0, 0);
      }
      __builtin_amdgcn_s_setprio(0);
    }

    __syncthreads();   // drains prefetch vmcnt + all waves done with buf
  }
#undef STAGE

  // epilogue: normalize, write ctx fp16 contiguous [M][2048]
#pragma unroll
  for (int rb = 0; rb < 2; ++rb)
#pragma unroll
    for (int n = 0; n < 8; ++n)
#pragma unroll
      for (int r = 0; r < 4; ++r) {
        float o = acc[rb][n][r] / accl[rb][r];
        int qi = qw + rb * 16 + rg * 4 + r;
        ctxf[(size_t)(b * S_ + qi) * D_ + h * HD_ + n * 16 + rr] = (f16)o;
      }
}

extern "C" void kernel_launch(void* const* d_in, const int* in_sizes, int n_in,
                              void* d_out, int out_size, void* d_ws, size_t ws_size,
                              hipStream_t stream) {
  const float* x    = (const float*)d_in[0];
  // d_in[1] = mask (recomputed analytically)
  const float* cosb = (const float*)d_in[2];
  const float* sinb = (const float*)d_in[3];
  const float* Wq   = (const float*)d_in[4];
  const float* Wk   = (const float*)d_in[5];
  const float* Wv   = (const float*)d_in[6];
  const float* Wo   = (const float*)d_in[7];
  const float* qsc  = (const float*)d_in[8];
  const float* ksc  = (const float*)d_in[9];
  float* out = (float*)d_out;

  char* ws = (char*)d_ws;
  const size_t MB = 1ull << 20;
  // [0,16)  xh fp16         -> after gemm0 reused: ctxf fp16
  // [16,28) wqkvT fp16      -> after gemm0 reused: kf[16,20) vb[20,24) vtb[24,28)
  // [28,36) woT fp16
  // [36,84) qkv f32
  f16* xh    = (f16*)(ws + 0 * MB);
  f16* ctxf  = (f16*)(ws + 0 * MB);
  f16* wqkvT = (f16*)(ws + 16 * MB);
  f16* kf    = (f16*)(ws + 16 * MB);
  f16* vb    = (f16*)(ws + 20 * MB);
  f16* vtb   = (f16*)(ws + 24 * MB);
  f16* woT   = (f16*)(ws + 28 * MB);
  float* qkv = (float*)(ws + 36 * MB);

  cast_f32_f16<<<dim3(M_ * D_ / 8 / 256), 256, 0, stream>>>(x, xh, M_ * D_ / 8);
  transpose_f32_f16<<<dim3(64, 64), 256, 0, stream>>>(Wq, wqkvT, D_, 2048);
  transpose_f32_f16<<<dim3(16, 64), 256, 0, stream>>>(Wk, wqkvT + (size_t)2048 * D_, D_, 512);
  transpose_f32_f16<<<dim3(16, 64), 256, 0, stream>>>(Wv, wqkvT + (size_t)2560 * D_, D_, 512);
  transpose_f32_f16<<<dim3(64, 64), 256, 0, stream>>>(Wo, woT, D_, D_);
  gemm_f16<<<dim3(NQKV_ / 128, M_ / 128), 256, 0, stream>>>(xh, wqkvT, qkv, M_, NQKV_, D_);
  norm_rope_kv<<<dim3(M_ * 8 / 4), 256, 0, stream>>>(qkv, cosb, sinb, ksc, kf, vb);
  transpose16<<<dim3(HD_ / 32, S_ / 32, B_ * KVH_), 256, 0, stream>>>(
      (const ushort_t*)vb, (ushort_t*)vtb, S_, HD_);
  flash_attn<<<dim3((S_ / QBLK) * H_ * B_), 256, 0, stream>>>(
      qkv, cosb, sinb, qsc, kf, vtb, ctxf);
  gemm_f16<<<dim3(D_ / 128, M_ / 128), 256, 0, stream>>>(ctxf, woT, out, M_, D_, D_);
}

// Round 11
// 206.376 us; speedup vs baseline: 1.7358x; 1.0790x over previous
//
#include <hip/hip_runtime.h>
#include <stdint.h>

#define B_ 2
#define S_ 2048
#define D_ 2048
#define H_ 16
#define KVH_ 4
#define HD_ 128
#define ROT_ 64
#define WINDOW_ 1024
#define EPS_ 1e-6f
#define M_ (B_ * S_)
#define NQKV_ 3072

#define QBLK 128
#define KVBLK 64
#define LOG2E 1.44269504088896340736f
#define DEFER_THR 8.0f

typedef unsigned short ushort_t;
typedef _Float16 f16;
typedef float f32x4 __attribute__((ext_vector_type(4)));
typedef float f32x16 __attribute__((ext_vector_type(16)));
typedef f16 f16x4 __attribute__((ext_vector_type(4)));
typedef f16 f16x8 __attribute__((ext_vector_type(8)));

#define NINF (-__builtin_inff())
#define EXP2F(x) __builtin_exp2f(x)

// async global->LDS, 16B per lane. dst must be wave-uniform; HW adds lane*16.
__device__ __forceinline__ void gload16(const void* g, void* l) {
  __builtin_amdgcn_global_load_lds(
      (const __attribute__((address_space(1))) void*)g,
      (__attribute__((address_space(3))) void*)l, 16, 0, 0);
}

// pack 2 f32 -> 1 u32 of 2 fp16 (rtz)
__device__ __forceinline__ int cvtpk_i(float a, float b) {
  auto h = __builtin_amdgcn_cvt_pkrtz(a, b);
  int r; __builtin_memcpy(&r, &h, 4); return r;
}

// ---------------- cast x (f32 -> f16), 8 elems/thread ----------------
__launch_bounds__(256, 4)
__global__ void cast_f32_f16(const float* __restrict__ src, f16* __restrict__ dst, int n8) {
  int i = blockIdx.x * 256 + threadIdx.x;
  if (i >= n8) return;
  float4 a = reinterpret_cast<const float4*>(src)[i * 2];
  float4 b = reinterpret_cast<const float4*>(src)[i * 2 + 1];
  f16x8 o = { (f16)a.x, (f16)a.y, (f16)a.z, (f16)a.w,
              (f16)b.x, (f16)b.y, (f16)b.z, (f16)b.w };
  reinterpret_cast<f16x8*>(dst)[i] = o;
}

// ---------------- transpose f32 [R][C] -> f16 [C][R] ----------------
__launch_bounds__(256, 4)
__global__ void transpose_f32_f16(const float* __restrict__ src, f16* __restrict__ dst,
                                  int R, int C) {
  __shared__ float tile[32][33];
  int c0 = blockIdx.x * 32, r0 = blockIdx.y * 32;
  int tx = threadIdx.x & 31, ty = threadIdx.x >> 5;
#pragma unroll
  for (int i = 0; i < 32; i += 8)
    tile[ty + i][tx] = src[(size_t)(r0 + ty + i) * C + c0 + tx];
  __syncthreads();
#pragma unroll
  for (int i = 0; i < 32; i += 8)
    dst[(size_t)(c0 + ty + i) * R + r0 + tx] = (f16)tile[tx][ty + i];
}

// ---------------- batched transpose 16-bit [R][C] -> [C][R] ----------------
__launch_bounds__(256, 4)
__global__ void transpose16(const ushort_t* __restrict__ src, ushort_t* __restrict__ dst,
                            int R, int C) {
  __shared__ ushort_t tile[32][33];
  size_t base = (size_t)blockIdx.z * R * C;
  src += base; dst += base;
  int c0 = blockIdx.x * 32, r0 = blockIdx.y * 32;
  int tx = threadIdx.x & 31, ty = threadIdx.x >> 5;
#pragma unroll
  for (int i = 0; i < 32; i += 8)
    tile[ty + i][tx] = src[(size_t)(r0 + ty + i) * C + c0 + tx];
  __syncthreads();
#pragma unroll
  for (int i = 0; i < 32; i += 8)
    dst[(size_t)(c0 + ty + i) * R + r0 + tx] = tile[tx][ty + i];
}

// ---------------- fp16 GEMM (round-5 proven): single-buffered, 2 barriers ------
__launch_bounds__(256, 2)
__global__ void gemm_f16(const f16* __restrict__ A, const f16* __restrict__ Bt,
                         float* __restrict__ C, int M, int N, int K) {
  __shared__ __attribute__((aligned(16))) f16 As[128][64];
  __shared__ __attribute__((aligned(16))) f16 Bs[128][64];
  const int gx = gridDim.x;
  const int nwg = gx * gridDim.y;
  const int flat = blockIdx.y * gx + blockIdx.x;
  const int q8 = nwg >> 3;
  const int id2 = (flat & 7) * q8 + (flat >> 3);
  const int bm = (id2 / gx) * 128, bn = (id2 % gx) * 128;
  const int tid = threadIdx.x;
  const int lane = tid & 63, wid = tid >> 6;
  const int wm = (wid >> 1) * 64, wn = (wid & 1) * 64;
  const int rr = lane & 15, rg = lane >> 4;
  const int sw = (((lane & 7) ^ (lane >> 3)) << 4);
  const int srw = lane >> 3;
  const char* Ab = (const char*)A + ((size_t)(bm + wid * 32 + srw) * K) * 2 + sw;
  const char* Bb = (const char*)Bt + ((size_t)(bn + wid * 32 + srw) * K) * 2 + sw;
  f32x4 acc[4][4] = {};
  for (int k0 = 0; k0 < K; k0 += 64) {
    __syncthreads();   // WAR: all waves done reading previous tile
#pragma unroll
    for (int g = 0; g < 4; ++g) {
      gload16(Ab + (size_t)(g * 8) * K * 2 + (size_t)k0 * 2,
              (char*)&As[0][0] + (wid * 32 + g * 8) * 128);
      gload16(Bb + (size_t)(g * 8) * K * 2 + (size_t)k0 * 2,
              (char*)&Bs[0][0] + (wid * 32 + g * 8) * 128);
    }
    __syncthreads();   // RAW: barrier drains vmcnt -> staged data visible
    f16x8 af[4][2], bf[4][2];
#pragma unroll
    for (int i = 0; i < 4; ++i)
#pragma unroll
      for (int kk = 0; kk < 2; ++kk) {
        af[i][kk] = *reinterpret_cast<const f16x8*>(
            (const char*)&As[0][0] + (wm + i * 16 + rr) * 128 +
            ((kk * 64 + rg * 16) ^ ((rr & 7) << 4)));
        bf[i][kk] = *reinterpret_cast<const f16x8*>(
            (const char*)&Bs[0][0] + (wn + i * 16 + rr) * 128 +
            ((kk * 64 + rg * 16) ^ ((rr & 7) << 4)));
      }
#pragma unroll
    for (int kk = 0; kk < 2; ++kk)
#pragma unroll
      for (int i = 0; i < 4; ++i)
#pragma unroll
        for (int j = 0; j < 4; ++j)
          acc[i][j] = __builtin_amdgcn_mfma_f32_16x16x32_f16(af[i][kk], bf[j][kk],
                                                             acc[i][j], 0, 0, 0);
  }
#pragma unroll
  for (int i = 0; i < 4; ++i)
#pragma unroll
    for (int j = 0; j < 4; ++j)
#pragma unroll
      for (int r = 0; r < 4; ++r)
        C[(size_t)(bm + wm + i * 16 + rg * 4 + r) * N + (bn + wn + j * 16 + rr)] = acc[i][j][r];
}

// ---------------- RMSNorm + RoPE for K and V, fp16 out ----------------
// K is pre-scaled by LOG2E so QK^T logits are in log2 units.
__launch_bounds__(256, 4)
__global__ void norm_rope_kv(const float* __restrict__ qkv, const float* __restrict__ cosb,
                             const float* __restrict__ sinb, const float* __restrict__ ksc,
                             f16* __restrict__ kf, f16* __restrict__ vb) {
  int gw = blockIdx.x * 4 + (threadIdx.x >> 6);
  int lane = threadIdx.x & 63;
  int row = gw >> 3, c = gw & 7;
  int b = row >> 11, s = row & (S_ - 1);
  int col = (c < 4) ? (2048 + c * 128) : (2560 + (c - 4) * 128);
  const float* src = qkv + (size_t)row * NQKV_ + col;
  float2 v = *reinterpret_cast<const float2*>(src + lane * 2);
  float ss = v.x * v.x + v.y * v.y;
#pragma unroll
  for (int off = 32; off; off >>= 1) ss += __shfl_xor(ss, off);
  float inv = rsqrtf(ss * (1.0f / HD_) + EPS_);
  float x0 = v.x * inv, x1 = v.y * inv;
  int d0 = lane * 2;
  f16* dst;
  size_t idx;
  if (c < 4) {  // k: (1+scale) then rope on dims [0,64), then *LOG2E
    x0 *= (1.0f + ksc[d0]);
    x1 *= (1.0f + ksc[d0 + 1]);
    float y0 = __shfl_xor(x0, 16);
    float y1 = __shfl_xor(x1, 16);
    if (d0 < ROT_) {
      int dm = d0 & 31;
      float cs0 = cosb[s * 32 + dm],     sn0 = sinb[s * 32 + dm];
      float cs1 = cosb[s * 32 + dm + 1], sn1 = sinb[s * 32 + dm + 1];
      if (d0 < 32) { x0 = x0 * cs0 - y0 * sn0; x1 = x1 * cs1 - y1 * sn1; }
      else         { x0 = x0 * cs0 + y0 * sn0; x1 = x1 * cs1 + y1 * sn1; }
    }
    x0 *= LOG2E; x1 *= LOG2E;
    dst = kf; idx = ((size_t)((b * KVH_ + c) * S_ + s)) * HD_ + d0;
  } else {      // v: plain rmsnorm
    dst = vb; idx = ((size_t)((b * KVH_ + (c - 4)) * S_ + s)) * HD_ + d0;
  }
  f16 o[2] = { (f16)x0, (f16)x1 };
  unsigned int pk; __builtin_memcpy(&pk, o, 4);
  *reinterpret_cast<unsigned int*>(dst + idx) = pk;
}

// ---------------- flash attention v8: swapped QK^T, in-register softmax ----------
// 512 blocks x 256 thr (4 waves x 32 q-rows). Staging/barriers as v7b.
// QK^T = mfma_32x32x16(K_frag, Q_frag) -> S^T: lane owns q=lane&31, 16 keys/regs
// (partner lane^32 holds complement). Softmax in-lane + one shfl_xor(32).
// P->B-frag via cvt_pkrtz + v_permlane32_swap_b32 (T12). PV = mfma(V^T, P^T) ->
// ctx^T in regs. No P LDS bounce, no shuffle trees, no accl MFMA.
__launch_bounds__(256, 2)
__global__ void flash_attn(const float* __restrict__ qkv, const float* __restrict__ cosb,
                           const float* __restrict__ sinb, const float* __restrict__ qsc,
                           const f16* __restrict__ kfp, const f16* __restrict__ vt,
                           f16* __restrict__ ctxf) {
  __shared__ __attribute__((aligned(16))) f16 Ks[2][KVBLK][128];   // 32 KB
  __shared__ __attribute__((aligned(16))) f16 Vs[2][128][KVBLK];   // 32 KB
  const int id = blockIdx.x;
  const int g8 = id & 7, rest = id >> 3;          // rest in [0,64)
  const int b = g8 >> 2, kvh = g8 & 3;
  int hh, qtile;
  if (rest < 32) { hh = rest >> 3; qtile = 8 + (rest & 7); }     // heavy: 18 tiles
  else { int lv = rest - 32; hh = lv >> 3; qtile = lv & 7; }     // light: 2..16
  const int h = kvh * 4 + hh;
  const int lane = threadIdx.x & 63, w = threadIdx.x >> 6;
  const int ql = lane & 31;          // this lane's q column
  const int hi = lane >> 5;          // half (0/1)
  const int qBase = qtile * QBLK;
  const int qw = qBase + w * 32;
  const int q = qw + ql;             // sequence position
  const f16* Kh = kfp + (size_t)(b * KVH_ + kvh) * S_ * HD_;
  const f16* Vh = vt  + (size_t)(b * KVH_ + kvh) * HD_ * S_;

  // ---- q prep: lane loads 64 f32 of row q (d = kk*16 + hi*8 + j), rmsnorm,
  //      scale, rope (lane-local pairs kk<->kk+2), cvt to B-frag layout ----
  f16x8 qf[8];
  {
    const float* qrow = qkv + (size_t)(b * S_ + q) * NQKV_ + h * HD_;
    float qv[8][8];
    float ssq = 0.f;
#pragma unroll
    for (int kk = 0; kk < 8; ++kk) {
      float4 u0 = *reinterpret_cast<const float4*>(qrow + kk * 16 + hi * 8);
      float4 u1 = *reinterpret_cast<const float4*>(qrow + kk * 16 + hi * 8 + 4);
      qv[kk][0] = u0.x; qv[kk][1] = u0.y; qv[kk][2] = u0.z; qv[kk][3] = u0.w;
      qv[kk][4] = u1.x; qv[kk][5] = u1.y; qv[kk][6] = u1.z; qv[kk][7] = u1.w;
#pragma unroll
      for (int j = 0; j < 8; ++j) ssq += qv[kk][j] * qv[kk][j];
    }
    ssq += __shfl_xor(ssq, 32);   // partner lane has the other 64 dims
    float inv = rsqrtf(ssq * (1.0f / HD_) + EPS_);
#pragma unroll
    for (int kk = 0; kk < 8; ++kk)
#pragma unroll
      for (int j = 0; j < 8; ++j)
        qv[kk][j] *= inv * (1.0f + qsc[kk * 16 + hi * 8 + j]);
    const float* cs = cosb + (size_t)q * 32;
    const float* sn = sinb + (size_t)q * 32;
#pragma unroll
    for (int kk = 0; kk < 2; ++kk)
#pragma unroll
      for (int j = 0; j < 8; ++j) {
        int d = kk * 16 + hi * 8 + j;          // in [0,32)
        float c = cs[d], s_ = sn[d];
        float x0 = qv[kk][j], x1 = qv[kk + 2][j];
        qv[kk][j]     = x0 * c - x1 * s_;
        qv[kk + 2][j] = x1 * c + x0 * s_;
      }
#pragma unroll
    for (int kk = 0; kk < 8; ++kk)
#pragma unroll
      for (int j = 0; j < 8; ++j)
        qf[kk][j] = (f16)qv[kk][j];
  }

  f32x16 acc[4] = {};
  float m_run = NINF, msafe = 0.f, l_run = 0.f;

  int kvStart = qBase - (WINDOW_ - 1);
  if (kvStart < 0) kvStart = 0;
  kvStart &= ~(KVBLK - 1);
  const int ntile = (qBase + QBLK - kvStart) >> 6;

  const int k_r0 = lane >> 4;          // 0..3
  const int k_cb = (lane & 15) * 16;
  const int v_r0 = lane >> 3;          // 0..7
  const int v_cb = (lane & 7) * 16;

#define STAGE(bufs, key0_)                                                           \
  do {                                                                               \
    _Pragma("unroll")                                                                \
    for (int gg = 0; gg < 4; ++gg) {                                                 \
      int krow = gg * 4 + k_r0;                                                      \
      gload16((const char*)Kh + (size_t)((key0_) + w * 16 + krow) * 256 +            \
                  (k_cb ^ ((krow & 7) << 4)),                                        \
              (char*)&Ks[bufs][0][0] + (w * 16 + gg * 4) * 256);                     \
      int vrow = gg * 8 + v_r0;                                                      \
      gload16((const char*)Vh + (size_t)(w * 32 + vrow) * (S_ * 2) +                 \
                  (size_t)(key0_) * 2 + (v_cb ^ ((vrow & 7) << 4)),                  \
              (char*)&Vs[bufs][0][0] + (w * 32 + gg * 8) * 128);                     \
    }                                                                                \
  } while (0)

  STAGE(0, kvStart);
  __syncthreads();

  for (int t = 0; t < ntile; ++t) {
    const int key0 = kvStart + t * KVBLK;
    const int buf = t & 1;
    if (t + 1 < ntile) STAGE(buf ^ 1, key0 + KVBLK);

    const bool live = (key0 <= qw + 31) && (key0 + 63 >= qw - (WINDOW_ - 1));
    if (live) {
      // ---- QK^T swapped: S^T[key][q], lane holds q=ql, keys via reg map ----
      f32x16 st[2];
#pragma unroll
      for (int kt = 0; kt < 2; ++kt) {
        const int rt = kt * 32 + ql;
        const char* kbase = (const char*)&Ks[buf][0][0] + rt * 256;
        const int swz = (rt & 7) << 4;
        f32x16 s = {};
#pragma unroll
        for (int kk = 0; kk < 8; ++kk) {
          f16x8 kfr = *reinterpret_cast<const f16x8*>(kbase + ((kk * 32 + hi * 16) ^ swz));
          s = __builtin_amdgcn_mfma_f32_32x32x16_f16(kfr, qf[kk], s, 0, 0, 0);
        }
        st[kt] = s;
      }

      // ---- mask (skipped for interior tiles); key = key0+kt*32+(r&3)+8(r>>2)+4hi ----
      const bool interior = (key0 + 63 <= qw) && (key0 >= qw - 992);
      if (!interior) {
#pragma unroll
        for (int kt = 0; kt < 2; ++kt)
#pragma unroll
          for (int r = 0; r < 16; ++r) {
            int kj = key0 + kt * 32 + ((r & 3) + 8 * (r >> 2) + 4 * hi);
            bool valid = (kj <= q) && (q - kj < WINDOW_);
            if (!valid) st[kt][r] = NINF;
          }
      }

      // ---- in-lane row max + one cross-half swap ----
      float tm = st[0][0];
#pragma unroll
      for (int r = 1; r < 16; ++r) tm = fmaxf(tm, st[0][r]);
#pragma unroll
      for (int r = 0; r < 16; ++r) tm = fmaxf(tm, st[1][r]);
      tm = fmaxf(tm, __shfl_xor(tm, 32));

      // ---- defer-max rescale ----
      bool defer = (tm - m_run <= DEFER_THR);
      if (!__all(defer)) {
        float mn = fmaxf(m_run, tm);
        float alpha = (m_run == NINF) ? 0.f : EXP2F(m_run - mn);
        m_run = mn;
        msafe = (mn == NINF) ? 0.f : mn;
#pragma unroll
        for (int dt = 0; dt < 4; ++dt)
#pragma unroll
          for (int r = 0; r < 16; ++r) acc[dt][r] *= alpha;
        l_run *= alpha;
      }
      // ---- exp (log2 domain) + row-sum ----
      float ps = 0.f;
#pragma unroll
      for (int kt = 0; kt < 2; ++kt)
#pragma unroll
        for (int r = 0; r < 16; ++r) {
          float p = EXP2F(st[kt][r] - msafe);
          st[kt][r] = p;
          ps += p;
        }
      ps += __shfl_xor(ps, 32);
      l_run += ps;

      // ---- P -> B-fragments in-register (cvt_pk + permlane32_swap) ----
      f16x8 pf[4];
#pragma unroll
      for (int ks = 0; ks < 4; ++ks) {
        const int kt = ks >> 1, rb = (ks & 1) * 8;
        int w0 = cvtpk_i(st[kt][rb + 0], st[kt][rb + 1]);
        int w2 = cvtpk_i(st[kt][rb + 4], st[kt][rb + 5]);
        asm volatile("v_permlane32_swap_b32 %0, %1" : "+v"(w0), "+v"(w2));
        int w1 = cvtpk_i(st[kt][rb + 2], st[kt][rb + 3]);
        int w3 = cvtpk_i(st[kt][rb + 6], st[kt][rb + 7]);
        asm volatile("v_permlane32_swap_b32 %0, %1" : "+v"(w1), "+v"(w3));
        int wi[4] = { w0, w1, w2, w3 };
        __builtin_memcpy(&pf[ks], wi, 16);
      }

      // ---- PV swapped: ctx^T[d][q] += V^T-frag x P^T-frag ----
      __builtin_amdgcn_s_setprio(1);
#pragma unroll
      for (int dt = 0; dt < 4; ++dt) {
        const int d = dt * 32 + ql;
        const char* vbase = (const char*)&Vs[buf][0][0] + d * 128;
        const int swz = (d & 7) << 4;
#pragma unroll
        for (int ks = 0; ks < 4; ++ks) {
          f16x8 vf = *reinterpret_cast<const f16x8*>(vbase + ((ks * 32 + hi * 16) ^ swz));
          acc[dt] = __builtin_amdgcn_mfma_f32_32x32x16_f16(vf, pf[ks], acc[dt], 0, 0, 0);
        }
      }
      __builtin_amdgcn_s_setprio(0);
    }

    __syncthreads();   // drains prefetch vmcnt + all waves done with buf
  }
#undef STAGE

  // ---- epilogue: lane owns q; d = dt*32 + 8*g + 4*hi + r -> 8B packed stores ----
  const float rinv = 1.0f / l_run;
  f16* orow = ctxf + (size_t)(b * S_ + q) * D_ + h * HD_;
#pragma unroll
  for (int dt = 0; dt < 4; ++dt)
#pragma unroll
    for (int g = 0; g < 4; ++g) {
      f16x4 o;
#pragma unroll
      for (int r = 0; r < 4; ++r) o[r] = (f16)(acc[dt][g * 4 + r] * rinv);
      *reinterpret_cast<f16x4*>(orow + dt * 32 + 8 * g + 4 * hi) = o;
    }
}

extern "C" void kernel_launch(void* const* d_in, const int* in_sizes, int n_in,
                              void* d_out, int out_size, void* d_ws, size_t ws_size,
                              hipStream_t stream) {
  const float* x    = (const float*)d_in[0];
  // d_in[1] = mask (recomputed analytically)
  const float* cosb = (const float*)d_in[2];
  const float* sinb = (const float*)d_in[3];
  const float* Wq   = (const float*)d_in[4];
  const float* Wk   = (const float*)d_in[5];
  const float* Wv   = (const float*)d_in[6];
  const float* Wo   = (const float*)d_in[7];
  const float* qsc  = (const float*)d_in[8];
  const float* ksc  = (const float*)d_in[9];
  float* out = (float*)d_out;

  char* ws = (char*)d_ws;
  const size_t MB = 1ull << 20;
  // [0,16)  xh fp16         -> after gemm0 reused: ctxf fp16
  // [16,28) wqkvT fp16      -> after gemm0 reused: kf[16,20) vb[20,24) vtb[24,28)
  // [28,36) woT fp16
  // [36,84) qkv f32
  f16* xh    = (f16*)(ws + 0 * MB);
  f16* ctxf  = (f16*)(ws + 0 * MB);
  f16* wqkvT = (f16*)(ws + 16 * MB);
  f16* kf    = (f16*)(ws + 16 * MB);
  f16* vb    = (f16*)(ws + 20 * MB);
  f16* vtb   = (f16*)(ws + 24 * MB);
  f16* woT   = (f16*)(ws + 28 * MB);
  float* qkv = (float*)(ws + 36 * MB);

  cast_f32_f16<<<dim3(M_ * D_ / 8 / 256), 256, 0, stream>>>(x, xh, M_ * D_ / 8);
  transpose_f32_f16<<<dim3(64, 64), 256, 0, stream>>>(Wq, wqkvT, D_, 2048);
  transpose_f32_f16<<<dim3(16, 64), 256, 0, stream>>>(Wk, wqkvT + (size_t)2048 * D_, D_, 512);
  transpose_f32_f16<<<dim3(16, 64), 256, 0, stream>>>(Wv, wqkvT + (size_t)2560 * D_, D_, 512);
  transpose_f32_f16<<<dim3(64, 64), 256, 0, stream>>>(Wo, woT, D_, D_);
  gemm_f16<<<dim3(NQKV_ / 128, M_ / 128), 256, 0, stream>>>(xh, wqkvT, qkv, M_, NQKV_, D_);
  norm_rope_kv<<<dim3(M_ * 8 / 4), 256, 0, stream>>>(qkv, cosb, sinb, ksc, kf, vb);
  transpose16<<<dim3(HD_ / 32, S_ / 32, B_ * KVH_), 256, 0, stream>>>(
      (const ushort_t*)vb, (ushort_t*)vtb, S_, HD_);
  flash_attn<<<dim3((S_ / QBLK) * H_ * B_), 256, 0, stream>>>(
      qkv, cosb, sinb, qsc, kf, vtb, ctxf);
  gemm_f16<<<dim3(D_ / 128, M_ / 128), 256, 0, stream>>>(ctxf, woT, out, M_, D_, D_);
}

// Round 12
// 202.453 us; speedup vs baseline: 1.7694x; 1.0194x over previous
//
#include <hip/hip_runtime.h>
#include <stdint.h>

#define B_ 2
#define S_ 2048
#define D_ 2048
#define H_ 16
#define KVH_ 4
#define HD_ 128
#define ROT_ 64
#define WINDOW_ 1024
#define EPS_ 1e-6f
#define M_ (B_ * S_)
#define NQKV_ 3072

#define QBLK 128
#define KVBLK 64
#define LOG2E 1.44269504088896340736f
#define DEFER_THR 8.0f

typedef unsigned short ushort_t;
typedef _Float16 f16;
typedef float f32x4 __attribute__((ext_vector_type(4)));
typedef float f32x16 __attribute__((ext_vector_type(16)));
typedef f16 f16x4 __attribute__((ext_vector_type(4)));
typedef f16 f16x8 __attribute__((ext_vector_type(8)));

#define NINF (-__builtin_inff())
#define EXP2F(x) __builtin_exp2f(x)

// async global->LDS, 16B per lane. dst must be wave-uniform; HW adds lane*16.
__device__ __forceinline__ void gload16(const void* g, void* l) {
  __builtin_amdgcn_global_load_lds(
      (const __attribute__((address_space(1))) void*)g,
      (__attribute__((address_space(3))) void*)l, 16, 0, 0);
}

// pack 2 f32 -> 1 u32 of 2 fp16 (rtz)
__device__ __forceinline__ int cvtpk_i(float a, float b) {
  auto h = __builtin_amdgcn_cvt_pkrtz(a, b);
  int r; __builtin_memcpy(&r, &h, 4); return r;
}

// ---------------- cast x (f32 -> f16), 8 elems/thread ----------------
__launch_bounds__(256, 4)
__global__ void cast_f32_f16(const float* __restrict__ src, f16* __restrict__ dst, int n8) {
  int i = blockIdx.x * 256 + threadIdx.x;
  if (i >= n8) return;
  float4 a = reinterpret_cast<const float4*>(src)[i * 2];
  float4 b = reinterpret_cast<const float4*>(src)[i * 2 + 1];
  f16x8 o = { (f16)a.x, (f16)a.y, (f16)a.z, (f16)a.w,
              (f16)b.x, (f16)b.y, (f16)b.z, (f16)b.w };
  reinterpret_cast<f16x8*>(dst)[i] = o;
}

// ---------------- transpose f32 [R][C] -> f16 [C][R] ----------------
__launch_bounds__(256, 4)
__global__ void transpose_f32_f16(const float* __restrict__ src, f16* __restrict__ dst,
                                  int R, int C) {
  __shared__ float tile[32][33];
  int c0 = blockIdx.x * 32, r0 = blockIdx.y * 32;
  int tx = threadIdx.x & 31, ty = threadIdx.x >> 5;
#pragma unroll
  for (int i = 0; i < 32; i += 8)
    tile[ty + i][tx] = src[(size_t)(r0 + ty + i) * C + c0 + tx];
  __syncthreads();
#pragma unroll
  for (int i = 0; i < 32; i += 8)
    dst[(size_t)(c0 + ty + i) * R + r0 + tx] = (f16)tile[tx][ty + i];
}

// ---------------- batched transpose 16-bit [R][C] -> [C][R] ----------------
__launch_bounds__(256, 4)
__global__ void transpose16(const ushort_t* __restrict__ src, ushort_t* __restrict__ dst,
                            int R, int C) {
  __shared__ ushort_t tile[32][33];
  size_t base = (size_t)blockIdx.z * R * C;
  src += base; dst += base;
  int c0 = blockIdx.x * 32, r0 = blockIdx.y * 32;
  int tx = threadIdx.x & 31, ty = threadIdx.x >> 5;
#pragma unroll
  for (int i = 0; i < 32; i += 8)
    tile[ty + i][tx] = src[(size_t)(r0 + ty + i) * C + c0 + tx];
  __syncthreads();
#pragma unroll
  for (int i = 0; i < 32; i += 8)
    dst[(size_t)(c0 + ty + i) * R + r0 + tx] = tile[tx][ty + i];
}

// ---------------- fp16 GEMM: single-buffered m97 structure, templated output ----
template<typename OT>
__launch_bounds__(256, 2)
__global__ void gemm_f16(const f16* __restrict__ A, const f16* __restrict__ Bt,
                         OT* __restrict__ C, int M, int N, int K) {
  __shared__ __attribute__((aligned(16))) f16 As[128][64];
  __shared__ __attribute__((aligned(16))) f16 Bs[128][64];
  const int gx = gridDim.x;
  const int nwg = gx * gridDim.y;
  const int flat = blockIdx.y * gx + blockIdx.x;
  const int q8 = nwg >> 3;
  const int id2 = (flat & 7) * q8 + (flat >> 3);
  const int bm = (id2 / gx) * 128, bn = (id2 % gx) * 128;
  const int tid = threadIdx.x;
  const int lane = tid & 63, wid = tid >> 6;
  const int wm = (wid >> 1) * 64, wn = (wid & 1) * 64;
  const int rr = lane & 15, rg = lane >> 4;
  const int sw = (((lane & 7) ^ (lane >> 3)) << 4);
  const int srw = lane >> 3;
  const char* Ab = (const char*)A + ((size_t)(bm + wid * 32 + srw) * K) * 2 + sw;
  const char* Bb = (const char*)Bt + ((size_t)(bn + wid * 32 + srw) * K) * 2 + sw;
  f32x4 acc[4][4] = {};
  for (int k0 = 0; k0 < K; k0 += 64) {
    __syncthreads();   // WAR: all waves done reading previous tile
#pragma unroll
    for (int g = 0; g < 4; ++g) {
      gload16(Ab + (size_t)(g * 8) * K * 2 + (size_t)k0 * 2,
              (char*)&As[0][0] + (wid * 32 + g * 8) * 128);
      gload16(Bb + (size_t)(g * 8) * K * 2 + (size_t)k0 * 2,
              (char*)&Bs[0][0] + (wid * 32 + g * 8) * 128);
    }
    __syncthreads();   // RAW: barrier drains vmcnt -> staged data visible
    f16x8 af[4][2], bf[4][2];
#pragma unroll
    for (int i = 0; i < 4; ++i)
#pragma unroll
      for (int kk = 0; kk < 2; ++kk) {
        af[i][kk] = *reinterpret_cast<const f16x8*>(
            (const char*)&As[0][0] + (wm + i * 16 + rr) * 128 +
            ((kk * 64 + rg * 16) ^ ((rr & 7) << 4)));
        bf[i][kk] = *reinterpret_cast<const f16x8*>(
            (const char*)&Bs[0][0] + (wn + i * 16 + rr) * 128 +
            ((kk * 64 + rg * 16) ^ ((rr & 7) << 4)));
      }
#pragma unroll
    for (int kk = 0; kk < 2; ++kk)
#pragma unroll
      for (int i = 0; i < 4; ++i)
#pragma unroll
        for (int j = 0; j < 4; ++j)
          acc[i][j] = __builtin_amdgcn_mfma_f32_16x16x32_f16(af[i][kk], bf[j][kk],
                                                             acc[i][j], 0, 0, 0);
  }
#pragma unroll
  for (int i = 0; i < 4; ++i)
#pragma unroll
    for (int j = 0; j < 4; ++j)
#pragma unroll
      for (int r = 0; r < 4; ++r)
        C[(size_t)(bm + wm + i * 16 + rg * 4 + r) * N + (bn + wn + j * 16 + rr)] =
            (OT)acc[i][j][r];
}

// ---------------- RMSNorm + RoPE for K and V, f16 in / f16 out ----------------
// K is pre-scaled by LOG2E so QK^T logits are in log2 units.
__launch_bounds__(256, 4)
__global__ void norm_rope_kv(const f16* __restrict__ qkv, const float* __restrict__ cosb,
                             const float* __restrict__ sinb, const float* __restrict__ ksc,
                             f16* __restrict__ kf, f16* __restrict__ vb) {
  int gw = blockIdx.x * 4 + (threadIdx.x >> 6);
  int lane = threadIdx.x & 63;
  int row = gw >> 3, c = gw & 7;
  int b = row >> 11, s = row & (S_ - 1);
  int col = (c < 4) ? (2048 + c * 128) : (2560 + (c - 4) * 128);
  const f16* src = qkv + (size_t)row * NQKV_ + col;
  unsigned int u = *reinterpret_cast<const unsigned int*>(src + lane * 2);
  f16 p2[2]; __builtin_memcpy(p2, &u, 4);
  float vx = (float)p2[0], vy = (float)p2[1];
  float ss = vx * vx + vy * vy;
#pragma unroll
  for (int off = 32; off; off >>= 1) ss += __shfl_xor(ss, off);
  float inv = rsqrtf(ss * (1.0f / HD_) + EPS_);
  float x0 = vx * inv, x1 = vy * inv;
  int d0 = lane * 2;
  f16* dst;
  size_t idx;
  if (c < 4) {  // k: (1+scale) then rope on dims [0,64), then *LOG2E
    x0 *= (1.0f + ksc[d0]);
    x1 *= (1.0f + ksc[d0 + 1]);
    float y0 = __shfl_xor(x0, 16);
    float y1 = __shfl_xor(x1, 16);
    if (d0 < ROT_) {
      int dm = d0 & 31;
      float cs0 = cosb[s * 32 + dm],     sn0 = sinb[s * 32 + dm];
      float cs1 = cosb[s * 32 + dm + 1], sn1 = sinb[s * 32 + dm + 1];
      if (d0 < 32) { x0 = x0 * cs0 - y0 * sn0; x1 = x1 * cs1 - y1 * sn1; }
      else         { x0 = x0 * cs0 + y0 * sn0; x1 = x1 * cs1 + y1 * sn1; }
    }
    x0 *= LOG2E; x1 *= LOG2E;
    dst = kf; idx = ((size_t)((b * KVH_ + c) * S_ + s)) * HD_ + d0;
  } else {      // v: plain rmsnorm
    dst = vb; idx = ((size_t)((b * KVH_ + (c - 4)) * S_ + s)) * HD_ + d0;
  }
  f16 o[2] = { (f16)x0, (f16)x1 };
  unsigned int pk; __builtin_memcpy(&pk, o, 4);
  *reinterpret_cast<unsigned int*>(dst + idx) = pk;
}

// ---------------- flash attention v8b: swapped QK^T, in-register softmax ----------
// Same as v8; q now read from f16 qkv (half the fetch).
__launch_bounds__(256, 2)
__global__ void flash_attn(const f16* __restrict__ qkv, const float* __restrict__ cosb,
                           const float* __restrict__ sinb, const float* __restrict__ qsc,
                           const f16* __restrict__ kfp, const f16* __restrict__ vt,
                           f16* __restrict__ ctxf) {
  __shared__ __attribute__((aligned(16))) f16 Ks[2][KVBLK][128];   // 32 KB
  __shared__ __attribute__((aligned(16))) f16 Vs[2][128][KVBLK];   // 32 KB
  const int id = blockIdx.x;
  const int g8 = id & 7, rest = id >> 3;          // rest in [0,64)
  const int b = g8 >> 2, kvh = g8 & 3;
  int hh, qtile;
  if (rest < 32) { hh = rest >> 3; qtile = 8 + (rest & 7); }     // heavy: 18 tiles
  else { int lv = rest - 32; hh = lv >> 3; qtile = lv & 7; }     // light: 2..16
  const int h = kvh * 4 + hh;
  const int lane = threadIdx.x & 63, w = threadIdx.x >> 6;
  const int ql = lane & 31;          // this lane's q column
  const int hi = lane >> 5;          // half (0/1)
  const int qBase = qtile * QBLK;
  const int qw = qBase + w * 32;
  const int q = qw + ql;             // sequence position
  const f16* Kh = kfp + (size_t)(b * KVH_ + kvh) * S_ * HD_;
  const f16* Vh = vt  + (size_t)(b * KVH_ + kvh) * HD_ * S_;

  // ---- q prep: lane loads 64 f16 of row q (d = kk*16 + hi*8 + j), rmsnorm,
  //      scale, rope (lane-local pairs kk<->kk+2), cvt to B-frag layout ----
  f16x8 qf[8];
  {
    const f16* qrow = qkv + (size_t)(b * S_ + q) * NQKV_ + h * HD_;
    float qv[8][8];
    float ssq = 0.f;
#pragma unroll
    for (int kk = 0; kk < 8; ++kk) {
      f16x8 u = *reinterpret_cast<const f16x8*>(qrow + kk * 16 + hi * 8);
#pragma unroll
      for (int j = 0; j < 8; ++j) {
        qv[kk][j] = (float)u[j];
        ssq += qv[kk][j] * qv[kk][j];
      }
    }
    ssq += __shfl_xor(ssq, 32);   // partner lane has the other 64 dims
    float inv = rsqrtf(ssq * (1.0f / HD_) + EPS_);
#pragma unroll
    for (int kk = 0; kk < 8; ++kk)
#pragma unroll
      for (int j = 0; j < 8; ++j)
        qv[kk][j] *= inv * (1.0f + qsc[kk * 16 + hi * 8 + j]);
    const float* cs = cosb + (size_t)q * 32;
    const float* sn = sinb + (size_t)q * 32;
#pragma unroll
    for (int kk = 0; kk < 2; ++kk)
#pragma unroll
      for (int j = 0; j < 8; ++j) {
        int d = kk * 16 + hi * 8 + j;          // in [0,32)
        float c = cs[d], s_ = sn[d];
        float x0 = qv[kk][j], x1 = qv[kk + 2][j];
        qv[kk][j]     = x0 * c - x1 * s_;
        qv[kk + 2][j] = x1 * c + x0 * s_;
      }
#pragma unroll
    for (int kk = 0; kk < 8; ++kk)
#pragma unroll
      for (int j = 0; j < 8; ++j)
        qf[kk][j] = (f16)qv[kk][j];
  }

  f32x16 acc[4] = {};
  float m_run = NINF, msafe = 0.f, l_run = 0.f;

  int kvStart = qBase - (WINDOW_ - 1);
  if (kvStart < 0) kvStart = 0;
  kvStart &= ~(KVBLK - 1);
  const int ntile = (qBase + QBLK - kvStart) >> 6;

  const int k_r0 = lane >> 4;          // 0..3
  const int k_cb = (lane & 15) * 16;
  const int v_r0 = lane >> 3;          // 0..7
  const int v_cb = (lane & 7) * 16;

#define STAGE(bufs, key0_)                                                           \
  do {                                                                               \
    _Pragma("unroll")                                                                \
    for (int gg = 0; gg < 4; ++gg) {                                                 \
      int krow = gg * 4 + k_r0;                                                      \
      gload16((const char*)Kh + (size_t)((key0_) + w * 16 + krow) * 256 +            \
                  (k_cb ^ ((krow & 7) << 4)),                                        \
              (char*)&Ks[bufs][0][0] + (w * 16 + gg * 4) * 256);                     \
      int vrow = gg * 8 + v_r0;                                                      \
      gload16((const char*)Vh + (size_t)(w * 32 + vrow) * (S_ * 2) +                 \
                  (size_t)(key0_) * 2 + (v_cb ^ ((vrow & 7) << 4)),                  \
              (char*)&Vs[bufs][0][0] + (w * 32 + gg * 8) * 128);                     \
    }                                                                                \
  } while (0)

  STAGE(0, kvStart);
  __syncthreads();

  for (int t = 0; t < ntile; ++t) {
    const int key0 = kvStart + t * KVBLK;
    const int buf = t & 1;
    if (t + 1 < ntile) STAGE(buf ^ 1, key0 + KVBLK);

    const bool live = (key0 <= qw + 31) && (key0 + 63 >= qw - (WINDOW_ - 1));
    if (live) {
      // ---- QK^T swapped: S^T[key][q], lane holds q=ql, keys via reg map ----
      f32x16 st[2];
#pragma unroll
      for (int kt = 0; kt < 2; ++kt) {
        const int rt = kt * 32 + ql;
        const char* kbase = (const char*)&Ks[buf][0][0] + rt * 256;
        const int swz = (rt & 7) << 4;
        f32x16 s = {};
#pragma unroll
        for (int kk = 0; kk < 8; ++kk) {
          f16x8 kfr = *reinterpret_cast<const f16x8*>(kbase + ((kk * 32 + hi * 16) ^ swz));
          s = __builtin_amdgcn_mfma_f32_32x32x16_f16(kfr, qf[kk], s, 0, 0, 0);
        }
        st[kt] = s;
      }

      // ---- mask (skipped for interior tiles); key = key0+kt*32+(r&3)+8(r>>2)+4hi ----
      const bool interior = (key0 + 63 <= qw) && (key0 >= qw - 992);
      if (!interior) {
#pragma unroll
        for (int kt = 0; kt < 2; ++kt)
#pragma unroll
          for (int r = 0; r < 16; ++r) {
            int kj = key0 + kt * 32 + ((r & 3) + 8 * (r >> 2) + 4 * hi);
            bool valid = (kj <= q) && (q - kj < WINDOW_);
            if (!valid) st[kt][r] = NINF;
          }
      }

      // ---- in-lane row max + one cross-half swap ----
      float tm = st[0][0];
#pragma unroll
      for (int r = 1; r < 16; ++r) tm = fmaxf(tm, st[0][r]);
#pragma unroll
      for (int r = 0; r < 16; ++r) tm = fmaxf(tm, st[1][r]);
      tm = fmaxf(tm, __shfl_xor(tm, 32));

      // ---- defer-max rescale ----
      bool defer = (tm - m_run <= DEFER_THR);
      if (!__all(defer)) {
        float mn = fmaxf(m_run, tm);
        float alpha = (m_run == NINF) ? 0.f : EXP2F(m_run - mn);
        m_run = mn;
        msafe = (mn == NINF) ? 0.f : mn;
#pragma unroll
        for (int dt = 0; dt < 4; ++dt)
#pragma unroll
          for (int r = 0; r < 16; ++r) acc[dt][r] *= alpha;
        l_run *= alpha;
      }
      // ---- exp (log2 domain) + row-sum ----
      float ps = 0.f;
#pragma unroll
      for (int kt = 0; kt < 2; ++kt)
#pragma unroll
        for (int r = 0; r < 16; ++r) {
          float p = EXP2F(st[kt][r] - msafe);
          st[kt][r] = p;
          ps += p;
        }
      ps += __shfl_xor(ps, 32);
      l_run += ps;

      // ---- P -> B-fragments in-register (cvt_pk + permlane32_swap) ----
      f16x8 pf[4];
#pragma unroll
      for (int ks = 0; ks < 4; ++ks) {
        const int kt = ks >> 1, rb = (ks & 1) * 8;
        int w0 = cvtpk_i(st[kt][rb + 0], st[kt][rb + 1]);
        int w2 = cvtpk_i(st[kt][rb + 4], st[kt][rb + 5]);
        asm volatile("v_permlane32_swap_b32 %0, %1" : "+v"(w0), "+v"(w2));
        int w1 = cvtpk_i(st[kt][rb + 2], st[kt][rb + 3]);
        int w3 = cvtpk_i(st[kt][rb + 6], st[kt][rb + 7]);
        asm volatile("v_permlane32_swap_b32 %0, %1" : "+v"(w1), "+v"(w3));
        int wi[4] = { w0, w1, w2, w3 };
        __builtin_memcpy(&pf[ks], wi, 16);
      }

      // ---- PV swapped: ctx^T[d][q] += V^T-frag x P^T-frag ----
      __builtin_amdgcn_s_setprio(1);
#pragma unroll
      for (int dt = 0; dt < 4; ++dt) {
        const int d = dt * 32 + ql;
        const char* vbase = (const char*)&Vs[buf][0][0] + d * 128;
        const int swz = (d & 7) << 4;
#pragma unroll
        for (int ks = 0; ks < 4; ++ks) {
          f16x8 vf = *reinterpret_cast<const f16x8*>(vbase + ((ks * 32 + hi * 16) ^ swz));
          acc[dt] = __builtin_amdgcn_mfma_f32_32x32x16_f16(vf, pf[ks], acc[dt], 0, 0, 0);
        }
      }
      __builtin_amdgcn_s_setprio(0);
    }

    __syncthreads();   // drains prefetch vmcnt + all waves done with buf
  }
#undef STAGE

  // ---- epilogue: lane owns q; d = dt*32 + 8*g + 4*hi + r -> 8B packed stores ----
  const float rinv = 1.0f / l_run;
  f16* orow = ctxf + (size_t)(b * S_ + q) * D_ + h * HD_;
#pragma unroll
  for (int dt = 0; dt < 4; ++dt)
#pragma unroll
    for (int g = 0; g < 4; ++g) {
      f16x4 o;
#pragma unroll
      for (int r = 0; r < 4; ++r) o[r] = (f16)(acc[dt][g * 4 + r] * rinv);
      *reinterpret_cast<f16x4*>(orow + dt * 32 + 8 * g + 4 * hi) = o;
    }
}

extern "C" void kernel_launch(void* const* d_in, const int* in_sizes, int n_in,
                              void* d_out, int out_size, void* d_ws, size_t ws_size,
                              hipStream_t stream) {
  const float* x    = (const float*)d_in[0];
  // d_in[1] = mask (recomputed analytically)
  const float* cosb = (const float*)d_in[2];
  const float* sinb = (const float*)d_in[3];
  const float* Wq   = (const float*)d_in[4];
  const float* Wk   = (const float*)d_in[5];
  const float* Wv   = (const float*)d_in[6];
  const float* Wo   = (const float*)d_in[7];
  const float* qsc  = (const float*)d_in[8];
  const float* ksc  = (const float*)d_in[9];
  float* out = (float*)d_out;

  char* ws = (char*)d_ws;
  const size_t MB = 1ull << 20;
  // [0,16)  xh fp16         -> after gemm0 reused: ctxf fp16
  // [16,28) wqkvT fp16      -> after gemm0 reused: kf[16,20) vb[20,24) vtb[24,28)
  // [28,36) woT fp16
  // [36,60) qkv fp16
  f16* xh    = (f16*)(ws + 0 * MB);
  f16* ctxf  = (f16*)(ws + 0 * MB);
  f16* wqkvT = (f16*)(ws + 16 * MB);
  f16* kf    = (f16*)(ws + 16 * MB);
  f16* vb    = (f16*)(ws + 20 * MB);
  f16* vtb   = (f16*)(ws + 24 * MB);
  f16* woT   = (f16*)(ws + 28 * MB);
  f16* qkvh  = (f16*)(ws + 36 * MB);

  cast_f32_f16<<<dim3(M_ * D_ / 8 / 256), 256, 0, stream>>>(x, xh, M_ * D_ / 8);
  transpose_f32_f16<<<dim3(64, 64), 256, 0, stream>>>(Wq, wqkvT, D_, 2048);
  transpose_f32_f16<<<dim3(16, 64), 256, 0, stream>>>(Wk, wqkvT + (size_t)2048 * D_, D_, 512);
  transpose_f32_f16<<<dim3(16, 64), 256, 0, stream>>>(Wv, wqkvT + (size_t)2560 * D_, D_, 512);
  transpose_f32_f16<<<dim3(64, 64), 256, 0, stream>>>(Wo, woT, D_, D_);
  gemm_f16<f16><<<dim3(NQKV_ / 128, M_ / 128), 256, 0, stream>>>(
      xh, wqkvT, qkvh, M_, NQKV_, D_);
  norm_rope_kv<<<dim3(M_ * 8 / 4), 256, 0, stream>>>(qkvh, cosb, sinb, ksc, kf, vb);
  transpose16<<<dim3(HD_ / 32, S_ / 32, B_ * KVH_), 256, 0, stream>>>(
      (const ushort_t*)vb, (ushort_t*)vtb, S_, HD_);
  flash_attn<<<dim3((S_ / QBLK) * H_ * B_), 256, 0, stream>>>(
      qkvh, cosb, sinb, qsc, kf, vtb, ctxf);
  gemm_f16<float><<<dim3(D_ / 128, M_ / 128), 256, 0, stream>>>(
      ctxf, woT, out, M_, D_, D_);
}